// Round 3
// baseline (791.160 us; speedup 1.0000x reference)
//
#include <hip/hip_runtime.h>
#include <stdint.h>

typedef __attribute__((ext_vector_type(4))) float f32x4;
typedef __attribute__((ext_vector_type(8))) __bf16 bf16x8;
typedef __attribute__((ext_vector_type(8))) unsigned short u16x8;

#define NTOK 1024
#define CDIM 1024

// expert order: 0=sp, 1=cp, 2=tm, 3=hs, 4=vs, 5=full-x (rmsnorm only)
// row-block table: sp rb[0,13) cp[13,17) tm[17,30) hs[30,34) vs[34,60) full[60,92)
__constant__ int cW[6]  = {400, 100, 400, 122, 801, 1024};
__constant__ int cS0[6] = {1, 801, 401, 901, 0, 0};
__constant__ int cR[6]  = {1600, 400, 1600, 488, 3204, 4096};
__constant__ int cRB[6] = {0, 13, 17, 30, 34, 60};

static __device__ __forceinline__ int find_e(int rbg) {
  if (rbg < 13) return 0;
  if (rbg < 17) return 1;
  if (rbg < 30) return 2;
  if (rbg < 34) return 3;
  if (rbg < 60) return 4;
  return 5;
}

struct EP {
  const float* nw[6];
  const float* b1[5];
  const float* b2[5];
};

static __device__ __forceinline__ unsigned short f2bf(float f) {
  unsigned u = __builtin_bit_cast(unsigned, f);
  u += 0x7fffu + ((u >> 16) & 1u);
  return (unsigned short)(u >> 16);
}

static __device__ __forceinline__ void gld16(const void* g, void* l) {
  __builtin_amdgcn_global_load_lds(
      (__attribute__((address_space(1))) void*)(uintptr_t)g,
      (__attribute__((address_space(3))) void*)(uintptr_t)l, 16, 0, 0);
}

// ---------------- fp32 -> bf16 convert (grid.x = n/1024, exact) --------------
__global__ __launch_bounds__(256) void cvt_kernel(const float* __restrict__ in,
                                                  unsigned short* __restrict__ outp) {
  const int i = (blockIdx.x * 256 + threadIdx.x) * 4;
  float4 v = *(const float4*)(in + i);
  ushort4 ov;
  ov.x = f2bf(v.x); ov.y = f2bf(v.y); ov.z = f2bf(v.z); ov.w = f2bf(v.w);
  *(ushort4*)(outp + i) = ov;
}

struct C4 { const float* s[4]; unsigned short* d[4]; };
__global__ __launch_bounds__(256) void cvt4_kernel(C4 c) {
  const int seg = blockIdx.y;
  const int i = (blockIdx.x * 256 + threadIdx.x) * 4;
  float4 v = *(const float4*)(c.s[seg] + i);
  ushort4 ov;
  ov.x = f2bf(v.x); ov.y = f2bf(v.y); ov.z = f2bf(v.z); ov.w = f2bf(v.w);
  *(ushort4*)(c.d[seg] + i) = ov;
}

// ------------- grouped RMSNorm + pack rows to padded bf16 matrix -------------
__global__ __launch_bounds__(256) void rmsnorm_group(const float* __restrict__ xb,
                                                     EP ep,
                                                     unsigned short* __restrict__ dst,
                                                     int rb_base) {
  const int r = blockIdx.x;
  const int tid = threadIdx.x;
  unsigned short* orow = dst + (size_t)r * CDIM;
  const int e = find_e((r >> 7) + rb_base);
  const int lr = r - (cRB[e] - rb_base) * 128;
  if (lr >= cR[e]) {
    ushort4 z; z.x = z.y = z.z = z.w = 0;
    ((ushort4*)orow)[tid] = z;
    return;
  }
  const int b = lr / cW[e];
  const int i = lr - b * cW[e];
  const float* row = xb + (size_t)(b * NTOK + cS0[e] + i) * CDIM;
  float4 v = ((const float4*)row)[tid];
  float ss = v.x * v.x + v.y * v.y + v.z * v.z + v.w * v.w;
#pragma unroll
  for (int d = 1; d < 64; d <<= 1) ss += __shfl_xor(ss, d, 64);
  __shared__ float red[4];
  if ((tid & 63) == 0) red[tid >> 6] = ss;
  __syncthreads();
  float tot = red[0] + red[1] + red[2] + red[3];
  float sc = rsqrtf(tot * (1.0f / 1024.0f) + 1e-6f);
  float4 wv = ((const float4*)ep.nw[e])[tid];
  ushort4 ov;
  ov.x = f2bf(v.x * sc * wv.x); ov.y = f2bf(v.y * sc * wv.y);
  ov.z = f2bf(v.z * sc * wv.z); ov.w = f2bf(v.w * sc * wv.w);
  ((ushort4*)orow)[tid] = ov;
}

// ---------------- GEMM: out[m][n] = sum_k A[m][k] * Bw[n][k] -----------------
// 128x128 tile, BK=32, 4 waves 2x2, 4x4 of 16x16x32 MFMA (m97 structure).
// 1D grid with XCD-aware decode: xcd = id&7 owns bn columns [xcd*nb, (xcd+1)*nb);
// within an XCD, bn cycles fastest -> co-resident blocks form a 2D patch whose
// B-columns stay L2-resident (per-XCD B working set <= ~1 MB per K-window).
// MODE 0: outb = bf16(acc)                                   (qkv)
// MODE 1: outf = res + acc + bias                            (proj + residual)
// MODE 2: grouped fc1: outb = bf16(silu(acc + b1[e]))
// MODE 3: grouped fc2: out[b, s0+i, n] += acc + b2[e][n]     (RMW, no atomics)
template <int MODE>
__global__ __launch_bounds__(256) void gemm_bt(const unsigned short* __restrict__ A,
                                               const unsigned short* __restrict__ Bw,
                                               EP ep,
                                               const float* __restrict__ bias,
                                               const float* __restrict__ res,
                                               float* __restrict__ outf,
                                               unsigned short* __restrict__ outb,
                                               int Nn, int K, int rb_base, int e0,
                                               int nb) {
  __shared__ unsigned short As[128 * 32];
  __shared__ unsigned short Bs[128 * 32];
  const int tid = threadIdx.x;
  const int lane = tid & 63;
  const int w = tid >> 6;
  const int quad = lane >> 4, l16 = lane & 15;
  const int wm = (w >> 1) * 64, wn = (w & 1) * 64;

  const int id = blockIdx.x;
  const int xcd = id & 7;
  const int r0 = id >> 3;
  const int bn = xcd * nb + r0 % nb;
  const int bm = r0 / nb;

  int e = 0;
  const unsigned short* Bp = Bw;
  const float* bp = bias;
  if (MODE >= 2) {
    e = find_e(bm + rb_base);
    Bp = Bw + (size_t)(e - e0) * (4096 * 1024);
    bp = (MODE == 2) ? ep.b1[e] : ep.b2[e];
  }

  const int c0 = tid, c1 = tid + 256;
  const size_t aoff0 = (size_t)(bm * 128 + (c0 >> 2)) * K + (c0 & 3) * 8;
  const size_t aoff1 = (size_t)(bm * 128 + (c1 >> 2)) * K + (c1 & 3) * 8;
  const size_t boff0 = (size_t)(bn * 128 + (c0 >> 2)) * K + (c0 & 3) * 8;
  const size_t boff1 = (size_t)(bn * 128 + (c1 >> 2)) * K + (c1 & 3) * 8;

  f32x4 acc[4][4] = {};

  for (int kt = 0; kt < K; kt += 32) {
    gld16(A + aoff0 + kt, &As[c0 * 8]);
    gld16(A + aoff1 + kt, &As[c1 * 8]);
    gld16(Bp + boff0 + kt, &Bs[c0 * 8]);
    gld16(Bp + boff1 + kt, &Bs[c1 * 8]);
    __syncthreads();
    bf16x8 af[4], bfr[4];
#pragma unroll
    for (int i = 0; i < 4; i++)
      af[i] = *(const bf16x8*)&As[(wm + i * 16 + l16) * 32 + quad * 8];
#pragma unroll
    for (int j = 0; j < 4; j++)
      bfr[j] = *(const bf16x8*)&Bs[(wn + j * 16 + l16) * 32 + quad * 8];
#pragma unroll
    for (int i = 0; i < 4; i++)
#pragma unroll
      for (int j = 0; j < 4; j++)
        acc[i][j] = __builtin_amdgcn_mfma_f32_16x16x32_bf16(af[i], bfr[j], acc[i][j], 0, 0, 0);
    __syncthreads();
  }

  float bj[4] = {0, 0, 0, 0};
  if (MODE >= 1) {
#pragma unroll
    for (int j = 0; j < 4; j++) bj[j] = bp[bn * 128 + wn + j * 16 + l16];
  }

  // C/D layout: row = quad*4 + reg, col = l16
  if (MODE == 3) {
    const int shift = (cRB[e] - rb_base) * 128;
#pragma unroll
    for (int i = 0; i < 4; i++) {
#pragma unroll
      for (int r = 0; r < 4; r++) {
        const int m = bm * 128 + wm + i * 16 + quad * 4 + r;
        const int lr = m - shift;
        if (lr < cR[e]) {
          const int bb = lr / cW[e];
          const int ii = lr - bb * cW[e];
          float* orow = outf + ((size_t)(bb * NTOK + cS0[e] + ii) << 10);
#pragma unroll
          for (int j = 0; j < 4; j++) {
            const int ncol = bn * 128 + wn + j * 16 + l16;
            orow[ncol] += acc[i][j][r] + bj[j];
          }
        }
      }
    }
  } else {
#pragma unroll
    for (int i = 0; i < 4; i++) {
      const int mbase = bm * 128 + wm + i * 16 + quad * 4;
#pragma unroll
      for (int j = 0; j < 4; j++) {
        const int ncol = bn * 128 + wn + j * 16 + l16;
#pragma unroll
        for (int r = 0; r < 4; r++) {
          const int m = mbase + r;
          float v = acc[i][j][r];
          if (MODE == 0) {
            outb[(size_t)m * Nn + ncol] = f2bf(v);
          } else if (MODE == 1) {
            const size_t idx = (size_t)m * Nn + ncol;
            outf[idx] = res[idx] + v + bj[j];
          } else {  // MODE 2
            float t = v + bj[j];
            float sg = 1.0f / (1.0f + __expf(-t));
            outb[(size_t)m * Nn + ncol] = f2bf(t * sg);
          }
        }
      }
    }
  }
}

// --------------------------- flash attention ---------------------------------
__global__ __launch_bounds__(256) void attn_kernel(const unsigned short* __restrict__ qkv,
                                                   unsigned short* __restrict__ o) {
  __shared__ unsigned short Ks[64 * 64];
  __shared__ unsigned short Vt[64 * 72];
  __shared__ unsigned short Ps[4][16 * 72];

  const int tid = threadIdx.x;
  const int w = tid >> 6, lane = tid & 63;
  const int quad = lane >> 4, l16 = lane & 15;
  const int blk = blockIdx.x;
  const int qt = blk & 15;
  const int bh = blk >> 4;
  const int b = bh >> 4, h = bh & 15;

  const unsigned short* qrow =
      qkv + ((size_t)b * NTOK + qt * 64 + w * 16 + l16) * 3072 + h * 64;
  bf16x8 qf0 = *(const bf16x8*)(qrow + quad * 8);
  bf16x8 qf1 = *(const bf16x8*)(qrow + 32 + quad * 8);

  f32x4 oacc[4] = {};
  float mrow[4], lrow[4];
#pragma unroll
  for (int r = 0; r < 4; r++) { mrow[r] = -1e30f; lrow[r] = 0.0f; }

  for (int kt = 0; kt < NTOK; kt += 64) {
    for (int c = tid; c < 512; c += 256) {
      int row = c >> 3, d0 = (c & 7) * 8;
      const unsigned short* kbase =
          qkv + ((size_t)b * NTOK + kt + row) * 3072 + 1024 + h * 64 + d0;
      *(u16x8*)&Ks[row * 64 + d0] = *(const u16x8*)kbase;
      u16x8 vv = *(const u16x8*)(kbase + 1024);
#pragma unroll
      for (int e = 0; e < 8; e++) Vt[(d0 + e) * 72 + row] = vv[e];
    }
    __syncthreads();

    f32x4 s[4] = {};
#pragma unroll
    for (int j = 0; j < 4; j++) {
      bf16x8 kf0 = *(const bf16x8*)&Ks[(j * 16 + l16) * 64 + quad * 8];
      bf16x8 kf1 = *(const bf16x8*)&Ks[(j * 16 + l16) * 64 + 32 + quad * 8];
      s[j] = __builtin_amdgcn_mfma_f32_16x16x32_bf16(qf0, kf0, s[j], 0, 0, 0);
      s[j] = __builtin_amdgcn_mfma_f32_16x16x32_bf16(qf1, kf1, s[j], 0, 0, 0);
    }
#pragma unroll
    for (int j = 0; j < 4; j++) s[j] *= 0.125f;

#pragma unroll
    for (int r = 0; r < 4; r++) {
      float mx = fmaxf(fmaxf(s[0][r], s[1][r]), fmaxf(s[2][r], s[3][r]));
#pragma unroll
      for (int d = 1; d < 16; d <<= 1) mx = fmaxf(mx, __shfl_xor(mx, d, 64));
      float mn = fmaxf(mrow[r], mx);
      float al = __expf(mrow[r] - mn);
      mrow[r] = mn;
      float rs = 0.0f;
#pragma unroll
      for (int j = 0; j < 4; j++) {
        float pp = __expf(s[j][r] - mn);
        s[j][r] = pp;
        rs += pp;
      }
#pragma unroll
      for (int d = 1; d < 16; d <<= 1) rs += __shfl_xor(rs, d, 64);
      lrow[r] = lrow[r] * al + rs;
#pragma unroll
      for (int dd = 0; dd < 4; dd++) oacc[dd][r] *= al;
    }

    unsigned short* ps = Ps[w];
#pragma unroll
    for (int j = 0; j < 4; j++)
#pragma unroll
      for (int r = 0; r < 4; r++)
        ps[(quad * 4 + r) * 72 + j * 16 + l16] = f2bf(s[j][r]);
    __syncthreads();

#pragma unroll
    for (int ks = 0; ks < 2; ks++) {
      bf16x8 pf = *(const bf16x8*)&ps[l16 * 72 + ks * 32 + quad * 8];
#pragma unroll
      for (int dd = 0; dd < 4; dd++) {
        bf16x8 vf = *(const bf16x8*)&Vt[(dd * 16 + l16) * 72 + ks * 32 + quad * 8];
        oacc[dd] = __builtin_amdgcn_mfma_f32_16x16x32_bf16(pf, vf, oacc[dd], 0, 0, 0);
      }
    }
    __syncthreads();
  }

  unsigned short* orow = o + ((size_t)b * NTOK + qt * 64 + w * 16) * CDIM + h * 64;
#pragma unroll
  for (int r = 0; r < 4; r++) {
    float inv = 1.0f / lrow[r];
#pragma unroll
    for (int dd = 0; dd < 4; dd++)
      orow[(size_t)(quad * 4 + r) * CDIM + dd * 16 + l16] = f2bf(oacc[dd][r] * inv);
  }
}

// ----------------------------- orchestration ---------------------------------
extern "C" void kernel_launch(void* const* d_in, const int* in_sizes, int n_in,
                              void* d_out, int out_size, void* d_ws, size_t ws_size,
                              hipStream_t stream) {
  const float* x      = (const float*)d_in[0];
  const float* qkv_w  = (const float*)d_in[3];
  const float* proj_w = (const float*)d_in[4];
  const float* proj_b = (const float*)d_in[5];
  float* out = (float*)d_out;

  // expert input bases in dict order: sp=6, tm=11, vs=16, cp=21, hs=26
  // expert order here: 0=sp, 1=cp, 2=tm, 3=hs, 4=vs
  const int eb[5] = {6, 21, 11, 26, 16};
  EP ep;
  for (int e = 0; e < 5; e++) {
    ep.nw[e] = (const float*)d_in[eb[e] + 0];
    ep.b1[e] = (const float*)d_in[eb[e] + 2];
    ep.b2[e] = (const float*)d_in[eb[e] + 4];
  }
  ep.nw[5] = (const float*)d_in[2];  // norm_att_w

  char* p = (char*)d_ws;
  auto take = [&](size_t bytes) { char* r = p; p += (bytes + 255) & ~(size_t)255; return r; };
  unsigned short* wq   = (unsigned short*)take((size_t)3 * 1024 * 1024 * 2);   // 6.3 MB
  unsigned short* wp   = (unsigned short*)take((size_t)1024 * 1024 * 2);       // 2.1 MB
  unsigned short* wexp = (unsigned short*)take((size_t)4 * 4096 * 1024 * 2);   // 33.6 MB
  char* U = take((size_t)44600000);                                            // union region
  unsigned short* xn   = (unsigned short*)U;                    // dead after qkv gemm
  unsigned short* qkvb = (unsigned short*)(U + 8388608);        // dead after attn
  unsigned short* ob   = (unsigned short*)(U + 33554432);       // dead after proj
  unsigned short* fnb  = (unsigned short*)U;                    // alive post-proj
  unsigned short* hb   = (unsigned short*)(U + 8912896);        // alive post-proj

  // attention path
  cvt_kernel<<<3072, 256, 0, stream>>>(qkv_w, wq);
  cvt_kernel<<<1024, 256, 0, stream>>>(proj_w, wp);
  rmsnorm_group<<<4096, 256, 0, stream>>>(x, ep, xn, 60);
  gemm_bt<0><<<32 * 24, 256, 0, stream>>>(xn, wq, ep, nullptr, nullptr, nullptr, qkvb,
                                          3072, 1024, 0, 0, 3);
  attn_kernel<<<1024, 256, 0, stream>>>(qkvb, ob);
  gemm_bt<1><<<32 * 8, 256, 0, stream>>>(ob, wp, ep, proj_b, x, out, nullptr,
                                         1024, 1024, 0, 0, 1);

  // batched experts sp, cp, tm, hs (mutually disjoint slices)
  C4 c1, c2;
  for (int e = 0; e < 4; e++) {
    c1.s[e] = (const float*)d_in[eb[e] + 1];
    c1.d[e] = wexp + (size_t)e * 4096 * 1024;
    c2.s[e] = (const float*)d_in[eb[e] + 3];
    c2.d[e] = wexp + (size_t)e * 4096 * 1024;
  }
  cvt4_kernel<<<dim3(4096, 4), 256, 0, stream>>>(c1);
  rmsnorm_group<<<4352, 256, 0, stream>>>(out, ep, fnb, 0);
  gemm_bt<2><<<34 * 32, 256, 0, stream>>>(fnb, wexp, ep, nullptr, nullptr, nullptr, hb,
                                          4096, 1024, 0, 0, 4);
  cvt4_kernel<<<dim3(4096, 4), 256, 0, stream>>>(c2);  // w2 overwrites w1 slots (w1 consumed)
  gemm_bt<3><<<34 * 8, 256, 0, stream>>>(hb, wexp, ep, nullptr, nullptr, out, nullptr,
                                         1024, 4096, 0, 0, 1);

  // vs expert (depends on sp, tm outputs)
  cvt_kernel<<<4096, 256, 0, stream>>>((const float*)d_in[eb[4] + 1], wexp);
  rmsnorm_group<<<3328, 256, 0, stream>>>(out, ep, fnb, 34);
  gemm_bt<2><<<26 * 32, 256, 0, stream>>>(fnb, wexp, ep, nullptr, nullptr, nullptr, hb,
                                          4096, 1024, 34, 4, 4);
  cvt_kernel<<<4096, 256, 0, stream>>>((const float*)d_in[eb[4] + 3], wexp);
  gemm_bt<3><<<26 * 8, 256, 0, stream>>>(hb, wexp, ep, nullptr, nullptr, out, nullptr,
                                         1024, 4096, 34, 4, 1);
}

// Round 4
// 759.703 us; speedup vs baseline: 1.0414x; 1.0414x over previous
//
#include <hip/hip_runtime.h>
#include <stdint.h>

typedef __attribute__((ext_vector_type(4))) float f32x4;
typedef __attribute__((ext_vector_type(8))) __bf16 bf16x8;
typedef __attribute__((ext_vector_type(8))) unsigned short u16x8;

#define NTOK 1024
#define CDIM 1024

// expert order: 0=sp, 1=cp, 2=tm, 3=hs, 4=vs, 5=full-x (rmsnorm only)
// row-block table (128-row blocks): sp[0,13) cp[13,17) tm[17,30) hs[30,34) vs[34,60) full[60,92)
__constant__ int cW[6]  = {400, 100, 400, 122, 801, 1024};
__constant__ int cS0[6] = {1, 801, 401, 901, 0, 0};
__constant__ int cR[6]  = {1600, 400, 1600, 488, 3204, 4096};
__constant__ int cRB[6] = {0, 13, 17, 30, 34, 60};

static __device__ __forceinline__ int find_e(int rbg) {
  if (rbg < 13) return 0;
  if (rbg < 17) return 1;
  if (rbg < 30) return 2;
  if (rbg < 34) return 3;
  if (rbg < 60) return 4;
  return 5;
}

struct EP {
  const float* nw[6];
  const float* b1[5];
  const float* b2[5];
};

static __device__ __forceinline__ unsigned short f2bf(float f) {
  unsigned u = __builtin_bit_cast(unsigned, f);
  u += 0x7fffu + ((u >> 16) & 1u);
  return (unsigned short)(u >> 16);
}

static __device__ __forceinline__ void gld16(const void* g, void* l) {
  __builtin_amdgcn_global_load_lds(
      (__attribute__((address_space(1))) void*)(uintptr_t)g,
      (__attribute__((address_space(3))) void*)(uintptr_t)l, 16, 0, 0);
}

// ---------------- fp32 -> bf16 convert (grid.x = n/1024, exact) --------------
__global__ __launch_bounds__(256) void cvt_kernel(const float* __restrict__ in,
                                                  unsigned short* __restrict__ outp) {
  const int i = (blockIdx.x * 256 + threadIdx.x) * 4;
  float4 v = *(const float4*)(in + i);
  ushort4 ov;
  ov.x = f2bf(v.x); ov.y = f2bf(v.y); ov.z = f2bf(v.z); ov.w = f2bf(v.w);
  *(ushort4*)(outp + i) = ov;
}

struct C4 { const float* s[4]; unsigned short* d[4]; };
__global__ __launch_bounds__(256) void cvt4_kernel(C4 c) {
  const int seg = blockIdx.y;
  const int i = (blockIdx.x * 256 + threadIdx.x) * 4;
  float4 v = *(const float4*)(c.s[seg] + i);
  ushort4 ov;
  ov.x = f2bf(v.x); ov.y = f2bf(v.y); ov.z = f2bf(v.z); ov.w = f2bf(v.w);
  *(ushort4*)(c.d[seg] + i) = ov;
}

// ------------- grouped RMSNorm + pack rows to padded bf16 matrix -------------
__global__ __launch_bounds__(256) void rmsnorm_group(const float* __restrict__ xb,
                                                     EP ep,
                                                     unsigned short* __restrict__ dst,
                                                     int rb_base) {
  const int r = blockIdx.x;
  const int tid = threadIdx.x;
  unsigned short* orow = dst + (size_t)r * CDIM;
  const int e = find_e((r >> 7) + rb_base);
  const int lr = r - (cRB[e] - rb_base) * 128;
  if (lr >= cR[e]) {
    ushort4 z; z.x = z.y = z.z = z.w = 0;
    ((ushort4*)orow)[tid] = z;
    return;
  }
  const int b = lr / cW[e];
  const int i = lr - b * cW[e];
  const float* row = xb + (size_t)(b * NTOK + cS0[e] + i) * CDIM;
  float4 v = ((const float4*)row)[tid];
  float ss = v.x * v.x + v.y * v.y + v.z * v.z + v.w * v.w;
#pragma unroll
  for (int d = 1; d < 64; d <<= 1) ss += __shfl_xor(ss, d, 64);
  __shared__ float red[4];
  if ((tid & 63) == 0) red[tid >> 6] = ss;
  __syncthreads();
  float tot = red[0] + red[1] + red[2] + red[3];
  float sc = rsqrtf(tot * (1.0f / 1024.0f) + 1e-6f);
  float4 wv = ((const float4*)ep.nw[e])[tid];
  ushort4 ov;
  ov.x = f2bf(v.x * sc * wv.x); ov.y = f2bf(v.y * sc * wv.y);
  ov.z = f2bf(v.z * sc * wv.z); ov.w = f2bf(v.w * sc * wv.w);
  ((ushort4*)orow)[tid] = ov;
}

// ---------------- GEMM: out[m][n] = sum_k A[m][k] * Bw[n][k] -----------------
// BM=128 fixed, BN templated (128 or 64). BK=32. 4 waves in 2x2; each wave owns
// 64 x BN/2 of output = 4 x (BN/32) tiles of 16x16. BN=64 doubles grid size ->
// >=2 independent barrier groups per CU for latency hiding on small-N GEMMs.
// 1D grid, XCD decode: xcd=id&7 owns bn in [xcd*nb,(xcd+1)*nb), bn cycles fastest.
// MODE 0: outb = bf16(acc)                                   (qkv)
// MODE 1: outf = res + acc + bias                            (proj + residual)
// MODE 2: grouped fc1: outb = bf16(silu(acc + b1[e]))
// MODE 3: grouped fc2: out[b, s0+i, n] += acc + b2[e][n]     (RMW, no atomics)
template <int MODE, int BN>
__global__ __launch_bounds__(256) void gemm_bt(const unsigned short* __restrict__ A,
                                               const unsigned short* __restrict__ Bw,
                                               EP ep,
                                               const float* __restrict__ bias,
                                               const float* __restrict__ res,
                                               float* __restrict__ outf,
                                               unsigned short* __restrict__ outb,
                                               int Nn, int K, int rb_base, int e0,
                                               int nb) {
  constexpr int NT = BN / 32;           // per-wave N tiles
  constexpr int CHA = 128 * 4;          // A 16B-chunks per K-step
  constexpr int CHB = BN * 4;           // B 16B-chunks per K-step
  constexpr int NIT = (CHA + CHB) / 256;
  __shared__ unsigned short As[128 * 32];
  __shared__ unsigned short Bs[BN * 32];

  const int tid = threadIdx.x;
  const int lane = tid & 63;
  const int w = tid >> 6;
  const int quad = lane >> 4, l16 = lane & 15;
  const int wm = (w >> 1) * 64, wn = (w & 1) * (BN / 2);

  const int id = blockIdx.x;
  const int xcd = id & 7;
  const int r0 = id >> 3;
  const int bn = xcd * nb + r0 % nb;
  const int bm = r0 / nb;

  int e = 0;
  const unsigned short* Bp = Bw;
  const float* bp = bias;
  if (MODE >= 2) {
    e = find_e(bm + rb_base);
    Bp = Bw + (size_t)(e - e0) * (4096 * 1024);
    bp = (MODE == 2) ? ep.b1[e] : ep.b2[e];
  }

  // precompute staging pointers (lane-contiguous LDS per wave: chunk = tid + i*256,
  // CHA multiple of 64 so no wave straddles the As/Bs boundary)
  const unsigned short* gp[NIT];
  unsigned short* lp[NIT];
#pragma unroll
  for (int i = 0; i < NIT; i++) {
    const int c = tid + i * 256;
    if (c < CHA) {
      const int row = c >> 2, k8 = c & 3;
      lp[i] = &As[row * 32 + k8 * 8];
      gp[i] = A + (size_t)(bm * 128 + row) * K + k8 * 8;
    } else {
      const int cb = c - CHA;
      const int row = cb >> 2, k8 = cb & 3;
      lp[i] = &Bs[row * 32 + k8 * 8];
      gp[i] = Bp + (size_t)(bn * BN + row) * K + k8 * 8;
    }
  }

  f32x4 acc[4][NT] = {};

  for (int kt = 0; kt < K; kt += 32) {
#pragma unroll
    for (int i = 0; i < NIT; i++) gld16(gp[i] + kt, lp[i]);
    __syncthreads();
    bf16x8 af[4], bfr[NT];
#pragma unroll
    for (int i = 0; i < 4; i++)
      af[i] = *(const bf16x8*)&As[(wm + i * 16 + l16) * 32 + quad * 8];
#pragma unroll
    for (int j = 0; j < NT; j++)
      bfr[j] = *(const bf16x8*)&Bs[(wn + j * 16 + l16) * 32 + quad * 8];
#pragma unroll
    for (int i = 0; i < 4; i++)
#pragma unroll
      for (int j = 0; j < NT; j++)
        acc[i][j] = __builtin_amdgcn_mfma_f32_16x16x32_bf16(af[i], bfr[j], acc[i][j], 0, 0, 0);
    __syncthreads();
  }

  float bj[NT];
  if (MODE >= 1) {
#pragma unroll
    for (int j = 0; j < NT; j++) bj[j] = bp[bn * BN + wn + j * 16 + l16];
  }

  // C/D layout: row = quad*4 + reg, col = l16
  if (MODE == 3) {
    const int shift = (cRB[e] - rb_base) * 128;
#pragma unroll
    for (int i = 0; i < 4; i++) {
#pragma unroll
      for (int r = 0; r < 4; r++) {
        const int m = bm * 128 + wm + i * 16 + quad * 4 + r;
        const int lr = m - shift;
        if (lr < cR[e]) {
          const int bb = lr / cW[e];
          const int ii = lr - bb * cW[e];
          float* orow = outf + ((size_t)(bb * NTOK + cS0[e] + ii) << 10);
#pragma unroll
          for (int j = 0; j < NT; j++) {
            const int ncol = bn * BN + wn + j * 16 + l16;
            orow[ncol] += acc[i][j][r] + bj[j];
          }
        }
      }
    }
  } else {
#pragma unroll
    for (int i = 0; i < 4; i++) {
      const int mbase = bm * 128 + wm + i * 16 + quad * 4;
#pragma unroll
      for (int j = 0; j < NT; j++) {
        const int ncol = bn * BN + wn + j * 16 + l16;
#pragma unroll
        for (int r = 0; r < 4; r++) {
          const int m = mbase + r;
          float v = acc[i][j][r];
          if (MODE == 0) {
            outb[(size_t)m * Nn + ncol] = f2bf(v);
          } else if (MODE == 1) {
            const size_t idx = (size_t)m * Nn + ncol;
            outf[idx] = res[idx] + v + bj[j];
          } else {  // MODE 2
            float t = v + bj[j];
            float sg = 1.0f / (1.0f + __expf(-t));
            outb[(size_t)m * Nn + ncol] = f2bf(t * sg);
          }
        }
      }
    }
  }
}

// --------------------------- flash attention ---------------------------------
__global__ __launch_bounds__(256) void attn_kernel(const unsigned short* __restrict__ qkv,
                                                   unsigned short* __restrict__ o) {
  __shared__ unsigned short Ks[64 * 64];
  __shared__ unsigned short Vt[64 * 72];
  __shared__ unsigned short Ps[4][16 * 72];

  const int tid = threadIdx.x;
  const int w = tid >> 6, lane = tid & 63;
  const int quad = lane >> 4, l16 = lane & 15;
  const int blk = blockIdx.x;
  const int qt = blk & 15;
  const int bh = blk >> 4;
  const int b = bh >> 4, h = bh & 15;

  const unsigned short* qrow =
      qkv + ((size_t)b * NTOK + qt * 64 + w * 16 + l16) * 3072 + h * 64;
  bf16x8 qf0 = *(const bf16x8*)(qrow + quad * 8);
  bf16x8 qf1 = *(const bf16x8*)(qrow + 32 + quad * 8);

  f32x4 oacc[4] = {};
  float mrow[4], lrow[4];
#pragma unroll
  for (int r = 0; r < 4; r++) { mrow[r] = -1e30f; lrow[r] = 0.0f; }

  for (int kt = 0; kt < NTOK; kt += 64) {
    for (int c = tid; c < 512; c += 256) {
      int row = c >> 3, d0 = (c & 7) * 8;
      const unsigned short* kbase =
          qkv + ((size_t)b * NTOK + kt + row) * 3072 + 1024 + h * 64 + d0;
      *(u16x8*)&Ks[row * 64 + d0] = *(const u16x8*)kbase;
      u16x8 vv = *(const u16x8*)(kbase + 1024);
#pragma unroll
      for (int e = 0; e < 8; e++) Vt[(d0 + e) * 72 + row] = vv[e];
    }
    __syncthreads();

    f32x4 s[4] = {};
#pragma unroll
    for (int j = 0; j < 4; j++) {
      bf16x8 kf0 = *(const bf16x8*)&Ks[(j * 16 + l16) * 64 + quad * 8];
      bf16x8 kf1 = *(const bf16x8*)&Ks[(j * 16 + l16) * 64 + 32 + quad * 8];
      s[j] = __builtin_amdgcn_mfma_f32_16x16x32_bf16(qf0, kf0, s[j], 0, 0, 0);
      s[j] = __builtin_amdgcn_mfma_f32_16x16x32_bf16(qf1, kf1, s[j], 0, 0, 0);
    }
#pragma unroll
    for (int j = 0; j < 4; j++) s[j] *= 0.125f;

#pragma unroll
    for (int r = 0; r < 4; r++) {
      float mx = fmaxf(fmaxf(s[0][r], s[1][r]), fmaxf(s[2][r], s[3][r]));
#pragma unroll
      for (int d = 1; d < 16; d <<= 1) mx = fmaxf(mx, __shfl_xor(mx, d, 64));
      float mn = fmaxf(mrow[r], mx);
      float al = __expf(mrow[r] - mn);
      mrow[r] = mn;
      float rs = 0.0f;
#pragma unroll
      for (int j = 0; j < 4; j++) {
        float pp = __expf(s[j][r] - mn);
        s[j][r] = pp;
        rs += pp;
      }
#pragma unroll
      for (int d = 1; d < 16; d <<= 1) rs += __shfl_xor(rs, d, 64);
      lrow[r] = lrow[r] * al + rs;
#pragma unroll
      for (int dd = 0; dd < 4; dd++) oacc[dd][r] *= al;
    }

    unsigned short* ps = Ps[w];
#pragma unroll
    for (int j = 0; j < 4; j++)
#pragma unroll
      for (int r = 0; r < 4; r++)
        ps[(quad * 4 + r) * 72 + j * 16 + l16] = f2bf(s[j][r]);
    __syncthreads();

#pragma unroll
    for (int ks = 0; ks < 2; ks++) {
      bf16x8 pf = *(const bf16x8*)&ps[l16 * 72 + ks * 32 + quad * 8];
#pragma unroll
      for (int dd = 0; dd < 4; dd++) {
        bf16x8 vf = *(const bf16x8*)&Vt[(dd * 16 + l16) * 72 + ks * 32 + quad * 8];
        oacc[dd] = __builtin_amdgcn_mfma_f32_16x16x32_bf16(pf, vf, oacc[dd], 0, 0, 0);
      }
    }
    __syncthreads();
  }

  unsigned short* orow = o + ((size_t)b * NTOK + qt * 64 + w * 16) * CDIM + h * 64;
#pragma unroll
  for (int r = 0; r < 4; r++) {
    float inv = 1.0f / lrow[r];
#pragma unroll
    for (int dd = 0; dd < 4; dd++)
      orow[(size_t)(quad * 4 + r) * CDIM + dd * 16 + l16] = f2bf(oacc[dd][r] * inv);
  }
}

// ----------------------------- orchestration ---------------------------------
extern "C" void kernel_launch(void* const* d_in, const int* in_sizes, int n_in,
                              void* d_out, int out_size, void* d_ws, size_t ws_size,
                              hipStream_t stream) {
  const float* x      = (const float*)d_in[0];
  const float* qkv_w  = (const float*)d_in[3];
  const float* proj_w = (const float*)d_in[4];
  const float* proj_b = (const float*)d_in[5];
  float* out = (float*)d_out;

  // expert input bases in dict order: sp=6, tm=11, vs=16, cp=21, hs=26
  // expert order here: 0=sp, 1=cp, 2=tm, 3=hs, 4=vs
  const int eb[5] = {6, 21, 11, 26, 16};
  EP ep;
  for (int e = 0; e < 5; e++) {
    ep.nw[e] = (const float*)d_in[eb[e] + 0];
    ep.b1[e] = (const float*)d_in[eb[e] + 2];
    ep.b2[e] = (const float*)d_in[eb[e] + 4];
  }
  ep.nw[5] = (const float*)d_in[2];  // norm_att_w

  char* p = (char*)d_ws;
  auto take = [&](size_t bytes) { char* r = p; p += (bytes + 255) & ~(size_t)255; return r; };
  unsigned short* wq   = (unsigned short*)take((size_t)3 * 1024 * 1024 * 2);   // 6.3 MB
  unsigned short* wp   = (unsigned short*)take((size_t)1024 * 1024 * 2);       // 2.1 MB
  unsigned short* wexp = (unsigned short*)take((size_t)4 * 4096 * 1024 * 2);   // 33.6 MB
  char* U = take((size_t)44600000);                                            // union region
  unsigned short* xn   = (unsigned short*)U;                    // dead after qkv gemm
  unsigned short* qkvb = (unsigned short*)(U + 8388608);        // dead after attn
  unsigned short* ob   = (unsigned short*)(U + 33554432);       // dead after proj
  unsigned short* fnb  = (unsigned short*)U;                    // alive post-proj
  unsigned short* hb   = (unsigned short*)(U + 8912896);        // alive post-proj

  // attention path
  cvt_kernel<<<3072, 256, 0, stream>>>(qkv_w, wq);
  cvt_kernel<<<1024, 256, 0, stream>>>(proj_w, wp);
  rmsnorm_group<<<4096, 256, 0, stream>>>(x, ep, xn, 60);
  gemm_bt<0, 64><<<32 * 48, 256, 0, stream>>>(xn, wq, ep, nullptr, nullptr, nullptr, qkvb,
                                              3072, 1024, 0, 0, 6);
  attn_kernel<<<1024, 256, 0, stream>>>(qkvb, ob);
  gemm_bt<1, 64><<<32 * 16, 256, 0, stream>>>(ob, wp, ep, proj_b, x, out, nullptr,
                                              1024, 1024, 0, 0, 2);

  // batched experts sp, cp, tm, hs (mutually disjoint slices)
  C4 c1, c2;
  for (int e = 0; e < 4; e++) {
    c1.s[e] = (const float*)d_in[eb[e] + 1];
    c1.d[e] = wexp + (size_t)e * 4096 * 1024;
    c2.s[e] = (const float*)d_in[eb[e] + 3];
    c2.d[e] = wexp + (size_t)e * 4096 * 1024;
  }
  cvt4_kernel<<<dim3(4096, 4), 256, 0, stream>>>(c1);
  rmsnorm_group<<<4352, 256, 0, stream>>>(out, ep, fnb, 0);
  gemm_bt<2, 128><<<34 * 32, 256, 0, stream>>>(fnb, wexp, ep, nullptr, nullptr, nullptr, hb,
                                               4096, 1024, 0, 0, 4);
  cvt4_kernel<<<dim3(4096, 4), 256, 0, stream>>>(c2);  // w2 overwrites w1 slots (w1 consumed)
  gemm_bt<3, 64><<<34 * 16, 256, 0, stream>>>(hb, wexp, ep, nullptr, nullptr, out, nullptr,
                                              1024, 4096, 0, 0, 2);

  // vs expert (depends on sp, tm outputs)
  cvt_kernel<<<4096, 256, 0, stream>>>((const float*)d_in[eb[4] + 1], wexp);
  rmsnorm_group<<<3328, 256, 0, stream>>>(out, ep, fnb, 34);
  gemm_bt<2, 128><<<26 * 32, 256, 0, stream>>>(fnb, wexp, ep, nullptr, nullptr, nullptr, hb,
                                               4096, 1024, 34, 4, 4);
  cvt_kernel<<<4096, 256, 0, stream>>>((const float*)d_in[eb[4] + 3], wexp);
  gemm_bt<3, 64><<<26 * 16, 256, 0, stream>>>(hb, wexp, ep, nullptr, nullptr, out, nullptr,
                                              1024, 4096, 34, 4, 2);
}

// Round 5
// 686.312 us; speedup vs baseline: 1.1528x; 1.1069x over previous
//
#include <hip/hip_runtime.h>
#include <stdint.h>

typedef __attribute__((ext_vector_type(4))) float f32x4;
typedef __attribute__((ext_vector_type(8))) __bf16 bf16x8;
typedef __attribute__((ext_vector_type(8))) unsigned short u16x8;

#define NTOK 1024
#define CDIM 1024

// expert order: 0=sp, 1=cp, 2=tm, 3=hs, 4=vs, 5=full-x (rmsnorm only)
// row-block table (128-row blocks): sp[0,13) cp[13,17) tm[17,30) hs[30,34) vs[34,60) full[60,92)
__constant__ int cW[6]  = {400, 100, 400, 122, 801, 1024};
__constant__ int cS0[6] = {1, 801, 401, 901, 0, 0};
__constant__ int cR[6]  = {1600, 400, 1600, 488, 3204, 4096};
__constant__ int cRB[6] = {0, 13, 17, 30, 34, 60};

static __device__ __forceinline__ int find_e(int rbg) {
  if (rbg < 13) return 0;
  if (rbg < 17) return 1;
  if (rbg < 30) return 2;
  if (rbg < 34) return 3;
  if (rbg < 60) return 4;
  return 5;
}

struct EP {
  const float* nw[6];
  const float* b1[5];
  const float* b2[5];
};

static __device__ __forceinline__ unsigned short f2bf(float f) {
  unsigned u = __builtin_bit_cast(unsigned, f);
  u += 0x7fffu + ((u >> 16) & 1u);
  return (unsigned short)(u >> 16);
}

static __device__ __forceinline__ void gld16(const void* g, void* l) {
  __builtin_amdgcn_global_load_lds(
      (__attribute__((address_space(1))) void*)(uintptr_t)g,
      (__attribute__((address_space(3))) void*)(uintptr_t)l, 16, 0, 0);
}

// ---------------- fp32 -> bf16 convert (grid.x = n/1024, exact) --------------
__global__ __launch_bounds__(256) void cvt_kernel(const float* __restrict__ in,
                                                  unsigned short* __restrict__ outp) {
  const int i = (blockIdx.x * 256 + threadIdx.x) * 4;
  float4 v = *(const float4*)(in + i);
  ushort4 ov;
  ov.x = f2bf(v.x); ov.y = f2bf(v.y); ov.z = f2bf(v.z); ov.w = f2bf(v.w);
  *(ushort4*)(outp + i) = ov;
}

struct C4 { const float* s[4]; unsigned short* d[4]; };
__global__ __launch_bounds__(256) void cvt4_kernel(C4 c) {
  const int seg = blockIdx.y;
  const int i = (blockIdx.x * 256 + threadIdx.x) * 4;
  float4 v = *(const float4*)(c.s[seg] + i);
  ushort4 ov;
  ov.x = f2bf(v.x); ov.y = f2bf(v.y); ov.z = f2bf(v.z); ov.w = f2bf(v.w);
  *(ushort4*)(c.d[seg] + i) = ov;
}

// ------------- grouped RMSNorm + pack rows to padded bf16 matrix -------------
__global__ __launch_bounds__(256) void rmsnorm_group(const float* __restrict__ xb,
                                                     EP ep,
                                                     unsigned short* __restrict__ dst,
                                                     int rb_base) {
  const int r = blockIdx.x;
  const int tid = threadIdx.x;
  unsigned short* orow = dst + (size_t)r * CDIM;
  const int e = find_e((r >> 7) + rb_base);
  const int lr = r - (cRB[e] - rb_base) * 128;
  if (lr >= cR[e]) {
    ushort4 z; z.x = z.y = z.z = z.w = 0;
    ((ushort4*)orow)[tid] = z;
    return;
  }
  const int b = lr / cW[e];
  const int i = lr - b * cW[e];
  const float* row = xb + (size_t)(b * NTOK + cS0[e] + i) * CDIM;
  float4 v = ((const float4*)row)[tid];
  float ss = v.x * v.x + v.y * v.y + v.z * v.z + v.w * v.w;
#pragma unroll
  for (int d = 1; d < 64; d <<= 1) ss += __shfl_xor(ss, d, 64);
  __shared__ float red[4];
  if ((tid & 63) == 0) red[tid >> 6] = ss;
  __syncthreads();
  float tot = red[0] + red[1] + red[2] + red[3];
  float sc = rsqrtf(tot * (1.0f / 1024.0f) + 1e-6f);
  float4 wv = ((const float4*)ep.nw[e])[tid];
  ushort4 ov;
  ov.x = f2bf(v.x * sc * wv.x); ov.y = f2bf(v.y * sc * wv.y);
  ov.z = f2bf(v.z * sc * wv.z); ov.w = f2bf(v.w * sc * wv.w);
  ((ushort4*)orow)[tid] = ov;
}

// ---------------- GEMM: out[m][n] = sum_k A[m][k] * Bw[n][k] -----------------
// BM=128, BN in {128,64}, BK=64. 4 waves 2x2; per wave 4 x (BN/32) MFMA tiles.
// BK=64 halves barrier-drain count vs BK=32. Bank conflicts avoided via XOR
// swizzle folded into the GLOBAL pointer: physical LDS chunk (row,c) holds
// global k-chunk (c ^ (row&7)); gld16 dest stays wave-uniform + lane*16, and
// ds_read_b128 applies the same XOR -> 2-way (free) bank aliasing.
// 1D grid, XCD decode: xcd=id&7 owns bn in [xcd*nb,(xcd+1)*nb), bn fastest.
// MODE 0: outb = bf16(acc)                                   (qkv)
// MODE 1: outf = res + acc + bias                            (proj + residual)
// MODE 2: grouped fc1: outb = bf16(silu(acc + b1[e]))
// MODE 3: grouped fc2: out[b, s0+i, n] += acc + b2[e][n]     (RMW, no atomics)
template <int MODE, int BN>
__global__ __launch_bounds__(256) void gemm_bt(const unsigned short* __restrict__ A,
                                               const unsigned short* __restrict__ Bw,
                                               EP ep,
                                               const float* __restrict__ bias,
                                               const float* __restrict__ res,
                                               float* __restrict__ outf,
                                               unsigned short* __restrict__ outb,
                                               int Nn, int K, int rb_base, int e0,
                                               int nb) {
  constexpr int NT = BN / 32;           // per-wave N tiles
  constexpr int CHA = 128 * 8;          // A 16B-chunks per K-step (BK=64)
  constexpr int CHB = BN * 8;           // B 16B-chunks per K-step
  constexpr int NIT = (CHA + CHB) / 256;
  __shared__ unsigned short As[128 * 64];
  __shared__ unsigned short Bs[BN * 64];

  const int tid = threadIdx.x;
  const int lane = tid & 63;
  const int w = tid >> 6;
  const int quad = lane >> 4, l16 = lane & 15;
  const int wm = (w >> 1) * 64, wn = (w & 1) * (BN / 2);

  const int id = blockIdx.x;
  const int xcd = id & 7;
  const int r0 = id >> 3;
  const int bn = xcd * nb + r0 % nb;
  const int bm = r0 / nb;

  int e = 0;
  const unsigned short* Bp = Bw;
  const float* bp = bias;
  if (MODE >= 2) {
    e = find_e(bm + rb_base);
    Bp = Bw + (size_t)(e - e0) * (4096 * 1024);
    bp = (MODE == 2) ? ep.b1[e] : ep.b2[e];
  }

  // staging pointers; slot c = tid + i*256 (CHA % 256 == 0 so no wave straddles
  // the As/Bs boundary). Physical chunk (row, cc) <- global chunk cc^(row&7).
  const unsigned short* gp[NIT];
  unsigned short* lp[NIT];
#pragma unroll
  for (int i = 0; i < NIT; i++) {
    const int c = tid + i * 256;
    if (c < CHA) {
      const int row = c >> 3, cc = c & 7;
      lp[i] = &As[row * 64 + cc * 8];
      gp[i] = A + (size_t)(bm * 128 + row) * K + (cc ^ (row & 7)) * 8;
    } else {
      const int cb = c - CHA;
      const int row = cb >> 3, cc = cb & 7;
      lp[i] = &Bs[row * 64 + cc * 8];
      gp[i] = Bp + (size_t)(bn * BN + row) * K + (cc ^ (row & 7)) * 8;
    }
  }

  f32x4 acc[4][NT] = {};

  for (int kt = 0; kt < K; kt += 64) {
#pragma unroll
    for (int i = 0; i < NIT; i++) gld16(gp[i] + kt, lp[i]);
    __syncthreads();
#pragma unroll
    for (int kw = 0; kw < 2; kw++) {
      bf16x8 af[4], bfr[NT];
#pragma unroll
      for (int i = 0; i < 4; i++) {
        const int rr = wm + i * 16 + l16;
        const int cp_ = (kw * 4 + quad) ^ (rr & 7);
        af[i] = *(const bf16x8*)&As[rr * 64 + cp_ * 8];
      }
#pragma unroll
      for (int j = 0; j < NT; j++) {
        const int rn = wn + j * 16 + l16;
        const int cp_ = (kw * 4 + quad) ^ (rn & 7);
        bfr[j] = *(const bf16x8*)&Bs[rn * 64 + cp_ * 8];
      }
#pragma unroll
      for (int i = 0; i < 4; i++)
#pragma unroll
        for (int j = 0; j < NT; j++)
          acc[i][j] = __builtin_amdgcn_mfma_f32_16x16x32_bf16(af[i], bfr[j], acc[i][j], 0, 0, 0);
    }
    __syncthreads();
  }

  float bj[NT];
  if (MODE >= 1) {
#pragma unroll
    for (int j = 0; j < NT; j++) bj[j] = bp[bn * BN + wn + j * 16 + l16];
  }

  // C/D layout: row = quad*4 + reg, col = l16
  if (MODE == 3) {
    const int shift = (cRB[e] - rb_base) * 128;
#pragma unroll
    for (int i = 0; i < 4; i++) {
#pragma unroll
      for (int r = 0; r < 4; r++) {
        const int m = bm * 128 + wm + i * 16 + quad * 4 + r;
        const int lr = m - shift;
        if (lr < cR[e]) {
          const int bb = lr / cW[e];
          const int ii = lr - bb * cW[e];
          float* orow = outf + ((size_t)(bb * NTOK + cS0[e] + ii) << 10);
#pragma unroll
          for (int j = 0; j < NT; j++) {
            const int ncol = bn * BN + wn + j * 16 + l16;
            orow[ncol] += acc[i][j][r] + bj[j];
          }
        }
      }
    }
  } else {
#pragma unroll
    for (int i = 0; i < 4; i++) {
      const int mbase = bm * 128 + wm + i * 16 + quad * 4;
#pragma unroll
      for (int j = 0; j < NT; j++) {
        const int ncol = bn * BN + wn + j * 16 + l16;
#pragma unroll
        for (int r = 0; r < 4; r++) {
          const int m = mbase + r;
          float v = acc[i][j][r];
          if (MODE == 0) {
            outb[(size_t)m * Nn + ncol] = f2bf(v);
          } else if (MODE == 1) {
            const size_t idx = (size_t)m * Nn + ncol;
            outf[idx] = res[idx] + v + bj[j];
          } else {  // MODE 2
            float t = v + bj[j];
            float sg = 1.0f / (1.0f + __expf(-t));
            outb[(size_t)m * Nn + ncol] = f2bf(t * sg);
          }
        }
      }
    }
  }
}

// --------------------------- flash attention ---------------------------------
__global__ __launch_bounds__(256) void attn_kernel(const unsigned short* __restrict__ qkv,
                                                   unsigned short* __restrict__ o) {
  __shared__ unsigned short Ks[64 * 64];
  __shared__ unsigned short Vt[64 * 72];
  __shared__ unsigned short Ps[4][16 * 72];

  const int tid = threadIdx.x;
  const int w = tid >> 6, lane = tid & 63;
  const int quad = lane >> 4, l16 = lane & 15;
  const int blk = blockIdx.x;
  const int qt = blk & 15;
  const int bh = blk >> 4;
  const int b = bh >> 4, h = bh & 15;

  const unsigned short* qrow =
      qkv + ((size_t)b * NTOK + qt * 64 + w * 16 + l16) * 3072 + h * 64;
  bf16x8 qf0 = *(const bf16x8*)(qrow + quad * 8);
  bf16x8 qf1 = *(const bf16x8*)(qrow + 32 + quad * 8);

  f32x4 oacc[4] = {};
  float mrow[4], lrow[4];
#pragma unroll
  for (int r = 0; r < 4; r++) { mrow[r] = -1e30f; lrow[r] = 0.0f; }

  for (int kt = 0; kt < NTOK; kt += 64) {
    for (int c = tid; c < 512; c += 256) {
      int row = c >> 3, d0 = (c & 7) * 8;
      const unsigned short* kbase =
          qkv + ((size_t)b * NTOK + kt + row) * 3072 + 1024 + h * 64 + d0;
      *(u16x8*)&Ks[row * 64 + d0] = *(const u16x8*)kbase;
      u16x8 vv = *(const u16x8*)(kbase + 1024);
#pragma unroll
      for (int e = 0; e < 8; e++) Vt[(d0 + e) * 72 + row] = vv[e];
    }
    __syncthreads();

    f32x4 s[4] = {};
#pragma unroll
    for (int j = 0; j < 4; j++) {
      bf16x8 kf0 = *(const bf16x8*)&Ks[(j * 16 + l16) * 64 + quad * 8];
      bf16x8 kf1 = *(const bf16x8*)&Ks[(j * 16 + l16) * 64 + 32 + quad * 8];
      s[j] = __builtin_amdgcn_mfma_f32_16x16x32_bf16(qf0, kf0, s[j], 0, 0, 0);
      s[j] = __builtin_amdgcn_mfma_f32_16x16x32_bf16(qf1, kf1, s[j], 0, 0, 0);
    }
#pragma unroll
    for (int j = 0; j < 4; j++) s[j] *= 0.125f;

#pragma unroll
    for (int r = 0; r < 4; r++) {
      float mx = fmaxf(fmaxf(s[0][r], s[1][r]), fmaxf(s[2][r], s[3][r]));
#pragma unroll
      for (int d = 1; d < 16; d <<= 1) mx = fmaxf(mx, __shfl_xor(mx, d, 64));
      float mn = fmaxf(mrow[r], mx);
      float al = __expf(mrow[r] - mn);
      mrow[r] = mn;
      float rs = 0.0f;
#pragma unroll
      for (int j = 0; j < 4; j++) {
        float pp = __expf(s[j][r] - mn);
        s[j][r] = pp;
        rs += pp;
      }
#pragma unroll
      for (int d = 1; d < 16; d <<= 1) rs += __shfl_xor(rs, d, 64);
      lrow[r] = lrow[r] * al + rs;
#pragma unroll
      for (int dd = 0; dd < 4; dd++) oacc[dd][r] *= al;
    }

    unsigned short* ps = Ps[w];
#pragma unroll
    for (int j = 0; j < 4; j++)
#pragma unroll
      for (int r = 0; r < 4; r++)
        ps[(quad * 4 + r) * 72 + j * 16 + l16] = f2bf(s[j][r]);
    __syncthreads();

#pragma unroll
    for (int ks = 0; ks < 2; ks++) {
      bf16x8 pf = *(const bf16x8*)&ps[l16 * 72 + ks * 32 + quad * 8];
#pragma unroll
      for (int dd = 0; dd < 4; dd++) {
        bf16x8 vf = *(const bf16x8*)&Vt[(dd * 16 + l16) * 72 + ks * 32 + quad * 8];
        oacc[dd] = __builtin_amdgcn_mfma_f32_16x16x32_bf16(pf, vf, oacc[dd], 0, 0, 0);
      }
    }
    __syncthreads();
  }

  unsigned short* orow = o + ((size_t)b * NTOK + qt * 64 + w * 16) * CDIM + h * 64;
#pragma unroll
  for (int r = 0; r < 4; r++) {
    float inv = 1.0f / lrow[r];
#pragma unroll
    for (int dd = 0; dd < 4; dd++)
      orow[(size_t)(quad * 4 + r) * CDIM + dd * 16 + l16] = f2bf(oacc[dd][r] * inv);
  }
}

// ----------------------------- orchestration ---------------------------------
extern "C" void kernel_launch(void* const* d_in, const int* in_sizes, int n_in,
                              void* d_out, int out_size, void* d_ws, size_t ws_size,
                              hipStream_t stream) {
  const float* x      = (const float*)d_in[0];
  const float* qkv_w  = (const float*)d_in[3];
  const float* proj_w = (const float*)d_in[4];
  const float* proj_b = (const float*)d_in[5];
  float* out = (float*)d_out;

  // expert input bases in dict order: sp=6, tm=11, vs=16, cp=21, hs=26
  // expert order here: 0=sp, 1=cp, 2=tm, 3=hs, 4=vs
  const int eb[5] = {6, 21, 11, 26, 16};
  EP ep;
  for (int e = 0; e < 5; e++) {
    ep.nw[e] = (const float*)d_in[eb[e] + 0];
    ep.b1[e] = (const float*)d_in[eb[e] + 2];
    ep.b2[e] = (const float*)d_in[eb[e] + 4];
  }
  ep.nw[5] = (const float*)d_in[2];  // norm_att_w

  char* p = (char*)d_ws;
  auto take = [&](size_t bytes) { char* r = p; p += (bytes + 255) & ~(size_t)255; return r; };
  unsigned short* wq   = (unsigned short*)take((size_t)3 * 1024 * 1024 * 2);   // 6.3 MB
  unsigned short* wp   = (unsigned short*)take((size_t)1024 * 1024 * 2);       // 2.1 MB
  unsigned short* wexp = (unsigned short*)take((size_t)4 * 4096 * 1024 * 2);   // 33.6 MB
  char* U = take((size_t)44600000);                                            // union region
  unsigned short* xn   = (unsigned short*)U;                    // dead after qkv gemm
  unsigned short* qkvb = (unsigned short*)(U + 8388608);        // dead after attn
  unsigned short* ob   = (unsigned short*)(U + 33554432);       // dead after proj
  unsigned short* fnb  = (unsigned short*)U;                    // alive post-proj
  unsigned short* hb   = (unsigned short*)(U + 8912896);        // alive post-proj

  // attention path
  cvt_kernel<<<3072, 256, 0, stream>>>(qkv_w, wq);
  cvt_kernel<<<1024, 256, 0, stream>>>(proj_w, wp);
  rmsnorm_group<<<4096, 256, 0, stream>>>(x, ep, xn, 60);
  gemm_bt<0, 64><<<32 * 48, 256, 0, stream>>>(xn, wq, ep, nullptr, nullptr, nullptr, qkvb,
                                              3072, 1024, 0, 0, 6);
  attn_kernel<<<1024, 256, 0, stream>>>(qkvb, ob);
  gemm_bt<1, 64><<<32 * 16, 256, 0, stream>>>(ob, wp, ep, proj_b, x, out, nullptr,
                                              1024, 1024, 0, 0, 2);

  // batched experts sp, cp, tm, hs (mutually disjoint slices)
  C4 c1, c2;
  for (int e = 0; e < 4; e++) {
    c1.s[e] = (const float*)d_in[eb[e] + 1];
    c1.d[e] = wexp + (size_t)e * 4096 * 1024;
    c2.s[e] = (const float*)d_in[eb[e] + 3];
    c2.d[e] = wexp + (size_t)e * 4096 * 1024;
  }
  cvt4_kernel<<<dim3(4096, 4), 256, 0, stream>>>(c1);
  rmsnorm_group<<<4352, 256, 0, stream>>>(out, ep, fnb, 0);
  gemm_bt<2, 128><<<34 * 32, 256, 0, stream>>>(fnb, wexp, ep, nullptr, nullptr, nullptr, hb,
                                               4096, 1024, 0, 0, 4);
  cvt4_kernel<<<dim3(4096, 4), 256, 0, stream>>>(c2);  // w2 overwrites w1 slots (w1 consumed)
  gemm_bt<3, 64><<<34 * 16, 256, 0, stream>>>(hb, wexp, ep, nullptr, nullptr, out, nullptr,
                                              1024, 4096, 0, 0, 2);

  // vs expert (depends on sp, tm outputs)
  cvt_kernel<<<4096, 256, 0, stream>>>((const float*)d_in[eb[4] + 1], wexp);
  rmsnorm_group<<<3328, 256, 0, stream>>>(out, ep, fnb, 34);
  gemm_bt<2, 128><<<26 * 32, 256, 0, stream>>>(fnb, wexp, ep, nullptr, nullptr, nullptr, hb,
                                               4096, 1024, 34, 4, 4);
  cvt_kernel<<<4096, 256, 0, stream>>>((const float*)d_in[eb[4] + 3], wexp);
  gemm_bt<3, 64><<<26 * 16, 256, 0, stream>>>(hb, wexp, ep, nullptr, nullptr, out, nullptr,
                                              1024, 4096, 34, 4, 2);
}